// Round 1
// baseline (2488.648 us; speedup 1.0000x reference)
//
#include <hip/hip_runtime.h>

#define HIDDEN 3584
#define NH 28
#define NKV 4
#define HD 128
#define NREP 7
#define SEQ 2048
#define BATCH 2
#define MTOK (BATCH*SEQ)   // 4096

typedef __bf16 bf16x8 __attribute__((ext_vector_type(8)));
typedef float  f32x4  __attribute__((ext_vector_type(4)));

__device__ __forceinline__ unsigned short f2bf(float f){
    unsigned u = __builtin_bit_cast(unsigned, f);
    unsigned r = u + 0x7FFFu + ((u >> 16) & 1u);   // RNE
    return (unsigned short)(r >> 16);
}
__device__ __forceinline__ float bf2f(unsigned short h){
    unsigned u = ((unsigned)h) << 16;
    return __builtin_bit_cast(float, u);
}
// unpack 8 bf16 (in a uint4) -> 8 floats, 1 VALU op per element
__device__ __forceinline__ void unpack8(uint4 rw, float* f){
    unsigned a0=rw.x, a1=rw.y, a2=rw.z, a3=rw.w;
    f[0]=__builtin_bit_cast(float, a0<<16); f[1]=__builtin_bit_cast(float, a0&0xFFFF0000u);
    f[2]=__builtin_bit_cast(float, a1<<16); f[3]=__builtin_bit_cast(float, a1&0xFFFF0000u);
    f[4]=__builtin_bit_cast(float, a2<<16); f[5]=__builtin_bit_cast(float, a2&0xFFFF0000u);
    f[6]=__builtin_bit_cast(float, a3<<16); f[7]=__builtin_bit_cast(float, a3&0xFFFF0000u);
}

// ---------------- elementwise cast fp32 -> bf16 ----------------
__global__ void cast_f32_bf16(const float* __restrict__ x, unsigned short* __restrict__ y, int n4){
    int i = blockIdx.x * blockDim.x + threadIdx.x;
    if (i < n4){
        float4 v = ((const float4*)x)[i];
        ushort4 o; o.x=f2bf(v.x); o.y=f2bf(v.y); o.z=f2bf(v.z); o.w=f2bf(v.w);
        ((ushort4*)y)[i] = o;
    }
}

// ---------------- W [K][N] fp32 -> Wt [N][K] bf16 ----------------
__global__ void transpose_cast(const float* __restrict__ W, unsigned short* __restrict__ Wt,
                               int K, int N){
    __shared__ float t[32][33];
    int n0 = blockIdx.x * 32, k0 = blockIdx.y * 32;
    int tx = threadIdx.x, ty = threadIdx.y;      // (32,8)
    #pragma unroll
    for (int r = 0; r < 4; r++)
        t[ty + r*8][tx] = W[(size_t)(k0 + ty + r*8) * N + n0 + tx];
    __syncthreads();
    #pragma unroll
    for (int r = 0; r < 4; r++)
        Wt[(size_t)(n0 + ty + r*8) * K + k0 + tx] = f2bf(t[tx][ty + r*8]);
}

// ---------------- GEMM: C[M,N] = A[M,K] @ Bt[N,K]^T + bias ----------------
// A, Bt bf16; acc fp32; out fp32 or bf16. M,N mult of 128; K mult of 32.
#define LDT 40   // 32 + 8 pad (keeps 16B alignment: 80B row stride)
template<int OUT_BF16>
__global__ __launch_bounds__(256) void gemm_bt(const unsigned short* __restrict__ A,
                                               const unsigned short* __restrict__ Bt,
                                               const float* __restrict__ bias,
                                               void* __restrict__ C, int M, int N, int K){
    __shared__ unsigned short As[128*LDT];
    __shared__ unsigned short Bs[128*LDT];
    int tid = threadIdx.x;
    int bm = blockIdx.x, bn = blockIdx.y;
    int lane = tid & 63, wave = tid >> 6;
    int wm = wave >> 1, wn = wave & 1;
    int quad = lane >> 4, l16 = lane & 15;
    f32x4 acc[4][4] = {};
    const int arow = tid >> 2;            // 0..63
    const int ac   = (tid & 3) * 8;       // 0,8,16,24
    const unsigned short* Ag = A  + (size_t)(bm*128) * K;
    const unsigned short* Bg = Bt + (size_t)(bn*128) * K;

    for (int k0 = 0; k0 < K; k0 += 32){
        #pragma unroll
        for (int p = 0; p < 2; p++){
            int r = p*64 + arow;
            *(uint4*)&As[r*LDT + ac] = *(const uint4*)&Ag[(size_t)r*K + k0 + ac];
            *(uint4*)&Bs[r*LDT + ac] = *(const uint4*)&Bg[(size_t)r*K + k0 + ac];
        }
        __syncthreads();
        bf16x8 af[4], bf[4];
        #pragma unroll
        for (int t = 0; t < 4; t++){
            af[t] = *(const bf16x8*)&As[(wm*64 + t*16 + l16)*LDT + quad*8];
            bf[t] = *(const bf16x8*)&Bs[(wn*64 + t*16 + l16)*LDT + quad*8];
        }
        #pragma unroll
        for (int tm = 0; tm < 4; tm++)
            #pragma unroll
            for (int tn = 0; tn < 4; tn++)
                acc[tm][tn] = __builtin_amdgcn_mfma_f32_16x16x32_bf16(af[tm], bf[tn], acc[tm][tn], 0, 0, 0);
        __syncthreads();
    }
    // epilogue: D row = quad*4 + r, col = l16  (measured layout, learn_hip m89/m91)
    #pragma unroll
    for (int tn = 0; tn < 4; tn++){
        int col = bn*128 + wn*64 + tn*16 + l16;
        float bb = bias ? bias[col] : 0.f;
        #pragma unroll
        for (int tm = 0; tm < 4; tm++){
            int row0 = bm*128 + wm*64 + tm*16 + quad*4;
            #pragma unroll
            for (int r = 0; r < 4; r++){
                float v = acc[tm][tn][r] + bb;
                if (OUT_BF16) ((unsigned short*)C)[(size_t)(row0+r)*N + col] = f2bf(v);
                else          ((float*)C)[(size_t)(row0+r)*N + col] = v;
            }
        }
    }
}

// ---------------- RoPE in-place on bf16 [rows][nheads][128] ----------------
__global__ void rope_kernel(unsigned short* __restrict__ x, const float* __restrict__ cosp,
                            const float* __restrict__ sinp, int nheads, int total){
    int i = blockIdx.x * blockDim.x + threadIdx.x;
    if (i >= total) return;
    int d   = i & 63;
    int h   = (i >> 6) % nheads;
    int row = i / (64 * nheads);
    int s   = row & (SEQ - 1);
    size_t base = ((size_t)row * nheads + h) * HD;
    float x1 = bf2f(x[base + d]), x2 = bf2f(x[base + d + 64]);
    float c1 = cosp[s*HD + d],  c2 = cosp[s*HD + d + 64];
    float s1 = sinp[s*HD + d],  s2 = sinp[s*HD + d + 64];
    x[base + d]      = f2bf(x1 * c1 - x2 * s1);
    x[base + d + 64] = f2bf(x2 * c2 + x1 * s2);
}

// ---------------- flash attention, fp32 math, bf16 I/O ----------------
// grid (32 qtiles, 28 heads, 2 batch), 256 threads.
#define QPAD 136   // 128 + 8 bf16 pad (272B row stride, 16B aligned)
#define PPAD 68
__global__ __launch_bounds__(256) void attn_kernel(const unsigned short* __restrict__ q,
                                                   const unsigned short* __restrict__ k,
                                                   const unsigned short* __restrict__ v,
                                                   unsigned short* __restrict__ ao){
    __shared__ unsigned short Qs[64*QPAD];
    __shared__ unsigned short Ks[64*QPAD];
    __shared__ unsigned short Vs[64*QPAD];
    __shared__ float Ps[64*PPAD];
    int qt = gridDim.x - 1 - blockIdx.x;   // heavy tiles first
    int h = blockIdx.y, b = blockIdx.z;
    int g = h / NREP;
    int tid = threadIdx.x;
    int tx = tid & 15, ty = tid >> 4;
    const float scale = 0.08838834764831845f;   // 128^-0.5

    // stage Q tile (64 x 128 bf16)
    #pragma unroll
    for (int p = 0; p < 4; p++){
        int row = p*16 + (tid >> 4), c8 = tid & 15;
        size_t src = (((size_t)(b*SEQ + qt*64 + row)) * NH + h) * HD + c8*8;
        *(uint4*)&Qs[row*QPAD + c8*8] = *(const uint4*)&q[src];
    }

    float m_i[4], l_i[4], o[4][8];
    #pragma unroll
    for (int r = 0; r < 4; r++){
        m_i[r] = -1e30f; l_i[r] = 0.f;
        #pragma unroll
        for (int t = 0; t < 8; t++) o[r][t] = 0.f;
    }

    for (int kt = 0; kt <= qt; kt++){
        __syncthreads();   // prev PV done before K/V overwrite
        #pragma unroll
        for (int p = 0; p < 4; p++){
            int row = p*16 + (tid >> 4), c8 = tid & 15;
            size_t src = (((size_t)(b*SEQ + kt*64 + row)) * NKV + g) * HD + c8*8;
            *(uint4*)&Ks[row*QPAD + c8*8] = *(const uint4*)&k[src];
            *(uint4*)&Vs[row*QPAD + c8*8] = *(const uint4*)&v[src];
        }
        __syncthreads();

        // scores: rows r = ty*4+rr, keys j = tx + 16*jj
        float sc[4][4] = {};
        for (int d0 = 0; d0 < HD; d0 += 8){
            float qf[4][8];
            #pragma unroll
            for (int rr = 0; rr < 4; rr++){
                uint4 qraw = *(const uint4*)&Qs[(ty*4+rr)*QPAD + d0];
                unpack8(qraw, qf[rr]);
            }
            #pragma unroll
            for (int jj = 0; jj < 4; jj++){
                uint4 kraw = *(const uint4*)&Ks[(tx + 16*jj)*QPAD + d0];
                float kf[8]; unpack8(kraw, kf);
                #pragma unroll
                for (int rr = 0; rr < 4; rr++)
                    #pragma unroll
                    for (int t = 0; t < 8; t++) sc[rr][jj] += qf[rr][t] * kf[t];
            }
        }

        bool diag = (kt == qt);
        #pragma unroll
        for (int rr = 0; rr < 4; rr++){
            #pragma unroll
            for (int jj = 0; jj < 4; jj++){
                float s = sc[rr][jj] * scale;
                if (diag && (tx + 16*jj > ty*4 + rr)) s = -1e9f;
                sc[rr][jj] = s;
            }
            float rm = fmaxf(fmaxf(sc[rr][0], sc[rr][1]), fmaxf(sc[rr][2], sc[rr][3]));
            rm = fmaxf(rm, __shfl_xor(rm, 1));
            rm = fmaxf(rm, __shfl_xor(rm, 2));
            rm = fmaxf(rm, __shfl_xor(rm, 4));
            rm = fmaxf(rm, __shfl_xor(rm, 8));
            float newm = fmaxf(m_i[rr], rm);
            float alpha = __expf(m_i[rr] - newm);
            float rs = 0.f;
            #pragma unroll
            for (int jj = 0; jj < 4; jj++){
                float p = __expf(sc[rr][jj] - newm);
                sc[rr][jj] = p; rs += p;
            }
            rs += __shfl_xor(rs, 1);
            rs += __shfl_xor(rs, 2);
            rs += __shfl_xor(rs, 4);
            rs += __shfl_xor(rs, 8);
            l_i[rr] = l_i[rr]*alpha + rs;
            m_i[rr] = newm;
            #pragma unroll
            for (int t = 0; t < 8; t++) o[rr][t] *= alpha;
            #pragma unroll
            for (int jj = 0; jj < 4; jj++)
                Ps[(ty*4+rr)*PPAD + tx + 16*jj] = sc[rr][jj];
        }
        __syncthreads();

        // PV: dims d = tx*8 .. +7
        for (int j0 = 0; j0 < 64; j0 += 4){
            float vf[4][8];
            #pragma unroll
            for (int jj = 0; jj < 4; jj++){
                uint4 vr = *(const uint4*)&Vs[(j0+jj)*QPAD + tx*8];
                unpack8(vr, vf[jj]);
            }
            #pragma unroll
            for (int rr = 0; rr < 4; rr++){
                float4 p4 = *(const float4*)&Ps[(ty*4+rr)*PPAD + j0];
                float pa[4] = {p4.x, p4.y, p4.z, p4.w};
                #pragma unroll
                for (int jj = 0; jj < 4; jj++)
                    #pragma unroll
                    for (int t = 0; t < 8; t++) o[rr][t] += pa[jj] * vf[jj][t];
            }
        }
    }

    // epilogue
    #pragma unroll
    for (int rr = 0; rr < 4; rr++){
        float inv = 1.f / l_i[rr];
        unsigned short o8[8];
        #pragma unroll
        for (int t = 0; t < 8; t++) o8[t] = f2bf(o[rr][t] * inv);
        unsigned w0 = (unsigned)o8[0] | ((unsigned)o8[1] << 16);
        unsigned w1 = (unsigned)o8[2] | ((unsigned)o8[3] << 16);
        unsigned w2 = (unsigned)o8[4] | ((unsigned)o8[5] << 16);
        unsigned w3 = (unsigned)o8[6] | ((unsigned)o8[7] << 16);
        uint4 ov; ov.x = w0; ov.y = w1; ov.z = w2; ov.w = w3;
        size_t dst = (((size_t)(b*SEQ + qt*64 + ty*4 + rr)) * NH + h) * HD + tx*8;
        *(uint4*)&ao[dst] = ov;
    }
}

extern "C" void kernel_launch(void* const* d_in, const int* in_sizes, int n_in,
                              void* d_out, int out_size, void* d_ws, size_t ws_size,
                              hipStream_t stream){
    const float* hs   = (const float*)d_in[0];
    const float* cosp = (const float*)d_in[1];
    const float* sinp = (const float*)d_in[2];
    const float* Wq   = (const float*)d_in[3];
    const float* bq   = (const float*)d_in[4];
    const float* Wk   = (const float*)d_in[5];
    const float* bk   = (const float*)d_in[6];
    const float* Wv   = (const float*)d_in[7];
    const float* bv   = (const float*)d_in[8];
    const float* Wo   = (const float*)d_in[9];
    float* out = (float*)d_out;
    char* ws = (char*)d_ws;

    // workspace layout (bytes); hsb later reused as ao, Wqt later reused as Wot
    unsigned short* hsb = (unsigned short*)(ws + 0);          // 4096x3584 bf16 = 29,360,128
    unsigned short* Wqt = (unsigned short*)(ws + 29360128);   // 3584x3584 bf16 = 25,690,112
    unsigned short* Wkt = (unsigned short*)(ws + 55050240);   //  512x3584 bf16 =  3,670,016
    unsigned short* Wvt = (unsigned short*)(ws + 58720256);   //  512x3584 bf16 =  3,670,016
    unsigned short* qb  = (unsigned short*)(ws + 62390272);   // 4096x3584 bf16 = 29,360,128
    unsigned short* kb  = (unsigned short*)(ws + 91750400);   // 4096x512  bf16 =  4,194,304
    unsigned short* vb  = (unsigned short*)(ws + 95944704);   // 4096x512  bf16 =  4,194,304
    unsigned short* ao  = hsb;   // safe: hs bf16 consumed by QKV gemms before attn writes
    unsigned short* Wot = Wqt;   // safe: Wqt consumed by Q gemm before Wo transpose

    int n4 = MTOK * HIDDEN / 4;
    cast_f32_bf16<<<(n4 + 255) / 256, 256, 0, stream>>>(hs, hsb, n4);
    transpose_cast<<<dim3(112, 112), dim3(32, 8), 0, stream>>>(Wq, Wqt, HIDDEN, NH*HD);
    transpose_cast<<<dim3(16, 112),  dim3(32, 8), 0, stream>>>(Wk, Wkt, HIDDEN, NKV*HD);
    transpose_cast<<<dim3(16, 112),  dim3(32, 8), 0, stream>>>(Wv, Wvt, HIDDEN, NKV*HD);

    gemm_bt<1><<<dim3(32, 28), 256, 0, stream>>>(hsb, Wqt, bq, qb, MTOK, NH*HD,  HIDDEN);
    gemm_bt<1><<<dim3(32, 4),  256, 0, stream>>>(hsb, Wkt, bk, kb, MTOK, NKV*HD, HIDDEN);
    gemm_bt<1><<<dim3(32, 4),  256, 0, stream>>>(hsb, Wvt, bv, vb, MTOK, NKV*HD, HIDDEN);

    rope_kernel<<<(MTOK*NH*64  + 255) / 256, 256, 0, stream>>>(qb, cosp, sinp, NH,  MTOK*NH*64);
    rope_kernel<<<(MTOK*NKV*64 + 255) / 256, 256, 0, stream>>>(kb, cosp, sinp, NKV, MTOK*NKV*64);

    transpose_cast<<<dim3(112, 112), dim3(32, 8), 0, stream>>>(Wo, Wot, NH*HD, HIDDEN);

    attn_kernel<<<dim3(32, 28, 2), 256, 0, stream>>>(qb, kb, vb, ao);

    gemm_bt<0><<<dim3(32, 28), 256, 0, stream>>>(ao, Wot, nullptr, out, MTOK, HIDDEN, NH*HD);
}

// Round 3
// 1085.796 us; speedup vs baseline: 2.2920x; 2.2920x over previous
//
#include <hip/hip_runtime.h>

#define HIDDEN 3584
#define NH 28
#define NKV 4
#define HD 128
#define NREP 7
#define SEQ 2048
#define BATCH 2
#define MTOK (BATCH*SEQ)   // 4096

typedef __bf16 bf16x8 __attribute__((ext_vector_type(8)));
typedef float  f32x4  __attribute__((ext_vector_type(4)));

__device__ __forceinline__ unsigned short f2bf(float f){
    unsigned u = __builtin_bit_cast(unsigned, f);
    unsigned r = u + 0x7FFFu + ((u >> 16) & 1u);   // RNE
    return (unsigned short)(r >> 16);
}
__device__ __forceinline__ float bf2f(unsigned short h){
    unsigned u = ((unsigned)h) << 16;
    return __builtin_bit_cast(float, u);
}

// async global->LDS, 16B per lane; lds dest = wave-uniform base + lane*16
__device__ __forceinline__ void gload_lds16(const void* g, void* l){
    __builtin_amdgcn_global_load_lds(
        (const __attribute__((address_space(1))) void*)g,
        (__attribute__((address_space(3))) void*)l, 16, 0, 0);
}

// ---------------- elementwise cast fp32 -> bf16 ----------------
__global__ void cast_f32_bf16(const float* __restrict__ x, unsigned short* __restrict__ y, int n4){
    int i = blockIdx.x * blockDim.x + threadIdx.x;
    if (i < n4){
        float4 v = ((const float4*)x)[i];
        ushort4 o; o.x=f2bf(v.x); o.y=f2bf(v.y); o.z=f2bf(v.z); o.w=f2bf(v.w);
        ((ushort4*)y)[i] = o;
    }
}

// ---------------- W [K][N] fp32 -> Wt [N][K] bf16 ----------------
__global__ void transpose_cast(const float* __restrict__ W, unsigned short* __restrict__ Wt,
                               int K, int N){
    __shared__ float t[32][33];
    int n0 = blockIdx.x * 32, k0 = blockIdx.y * 32;
    int tx = threadIdx.x, ty = threadIdx.y;      // (32,8)
    #pragma unroll
    for (int r = 0; r < 4; r++)
        t[ty + r*8][tx] = W[(size_t)(k0 + ty + r*8) * N + n0 + tx];
    __syncthreads();
    #pragma unroll
    for (int r = 0; r < 4; r++)
        Wt[(size_t)(n0 + ty + r*8) * K + k0 + tx] = f2bf(t[tx][ty + r*8]);
}

// ---------------- v [B*S][512] bf16 -> vt [B*512][SEQ] bf16 ----------------
__global__ void transpose_v(const unsigned short* __restrict__ v, unsigned short* __restrict__ vt){
    __shared__ unsigned short t[32][33];
    int s0 = blockIdx.x * 32, c0 = blockIdx.y * 32, b = blockIdx.z;
    int tx = threadIdx.x, ty = threadIdx.y;      // (32,8)
    #pragma unroll
    for (int r = 0; r < 4; r++)
        t[ty + r*8][tx] = v[(size_t)(b*SEQ + s0 + ty + r*8) * (NKV*HD) + c0 + tx];
    __syncthreads();
    #pragma unroll
    for (int r = 0; r < 4; r++)
        vt[(size_t)(b*NKV*HD + c0 + ty + r*8) * SEQ + s0 + tx] = t[tx][ty + r*8];
}

// ---------------- GEMM: C[M,N] = A[M,K] @ Bt[N,K]^T + bias ----------------
// m97 structure: 128x128 tile, BK=32, global_load_lds width-16, unpadded LDS.
template<int OUT_BF16>
__global__ __launch_bounds__(256) void gemm_bt(const unsigned short* __restrict__ A,
                                               const unsigned short* __restrict__ Bt,
                                               const float* __restrict__ bias,
                                               void* __restrict__ C, int M, int N, int K){
    __shared__ unsigned short As[128*32];
    __shared__ unsigned short Bs[128*32];
    int tid = threadIdx.x;
    int bm = blockIdx.x, bn = blockIdx.y;
    int lane = tid & 63, wave = tid >> 6;
    int wm = wave >> 1, wn = wave & 1;
    int quad = lane >> 4, l16 = lane & 15;
    f32x4 acc[4][4] = {};
    const unsigned short* Ag = A  + (size_t)(bm*128) * K;
    const unsigned short* Bg = Bt + (size_t)(bn*128) * K;

    for (int k0 = 0; k0 < K; k0 += 32){
        __syncthreads();
        #pragma unroll
        for (int c = 0; c < 2; c++){
            int e = c*256 + tid;                 // 0..511
            int r = e >> 2, col = (e & 3) * 8;
            int lb = (c*256 + wave*64) * 8;      // wave-uniform LDS base (elems)
            gload_lds16(&Ag[(size_t)r*K + k0 + col], &As[lb]);
            gload_lds16(&Bg[(size_t)r*K + k0 + col], &Bs[lb]);
        }
        __syncthreads();
        bf16x8 af[4], bf[4];
        #pragma unroll
        for (int t = 0; t < 4; t++){
            af[t] = *(const bf16x8*)&As[(wm*64 + t*16 + l16)*32 + quad*8];
            bf[t] = *(const bf16x8*)&Bs[(wn*64 + t*16 + l16)*32 + quad*8];
        }
        #pragma unroll
        for (int tm = 0; tm < 4; tm++)
            #pragma unroll
            for (int tn = 0; tn < 4; tn++)
                acc[tm][tn] = __builtin_amdgcn_mfma_f32_16x16x32_bf16(af[tm], bf[tn], acc[tm][tn], 0, 0, 0);
    }
    // epilogue: D row = quad*4 + r, col = l16
    #pragma unroll
    for (int tn = 0; tn < 4; tn++){
        int col = bn*128 + wn*64 + tn*16 + l16;
        float bb = bias ? bias[col] : 0.f;
        #pragma unroll
        for (int tm = 0; tm < 4; tm++){
            int row0 = bm*128 + wm*64 + tm*16 + quad*4;
            #pragma unroll
            for (int r = 0; r < 4; r++){
                float v = acc[tm][tn][r] + bb;
                if (OUT_BF16) ((unsigned short*)C)[(size_t)(row0+r)*N + col] = f2bf(v);
                else          ((float*)C)[(size_t)(row0+r)*N + col] = v;
            }
        }
    }
}

// ---------------- RoPE in-place on bf16 [rows][nheads][128] ----------------
__global__ void rope_kernel(unsigned short* __restrict__ x, const float* __restrict__ cosp,
                            const float* __restrict__ sinp, int nheads, int total){
    int i = blockIdx.x * blockDim.x + threadIdx.x;
    if (i >= total) return;
    int d   = i & 63;
    int h   = (i >> 6) % nheads;
    int row = i / (64 * nheads);
    int s   = row & (SEQ - 1);
    size_t base = ((size_t)row * nheads + h) * HD;
    float x1 = bf2f(x[base + d]), x2 = bf2f(x[base + d + 64]);
    float c1 = cosp[s*HD + d],  c2 = cosp[s*HD + d + 64];
    float s1 = sinp[s*HD + d],  s2 = sinp[s*HD + d + 64];
    x[base + d]      = f2bf(x1 * c1 - x2 * s1);
    x[base + d + 64] = f2bf(x2 * c2 + x1 * s2);
}

// ---------------- MFMA flash attention ----------------
// grid (16 qtiles, 28 heads, 2 batch), 256 threads = 4 waves.
// Q-tile 128 (wave w owns rows w*32..+31, Q frags in regs), K-tile 64.
// Ks LDS: [kc8(16)][key(64)][8]  -> Ks[(kc8*64+key)*8+j] = K[key][kc8*8+j]
// Vs LDS: [kch(8)][d(128)][8]    -> Vs[(kch*128+d)*8+j]  = V[key=kch*8+j][d]
// Ps LDS: [qrow(128)][72]        (wave-private P round-trip, C-layout -> A-layout)
__global__ __launch_bounds__(256, 2) void attn_mfma(const unsigned short* __restrict__ q,
                                                    const unsigned short* __restrict__ k,
                                                    const unsigned short* __restrict__ vt,
                                                    unsigned short* __restrict__ ao){
    __shared__ unsigned short Ks[16*64*8];
    __shared__ unsigned short Vs[8*128*8];
    __shared__ unsigned short Ps[128*72];
    const int qt = (int)gridDim.x - 1 - (int)blockIdx.x;   // heavy tiles first
    const int h = blockIdx.y, b = blockIdx.z;
    const int g = h / NREP;
    const int tid = threadIdx.x;
    const int lane = tid & 63, w = tid >> 6;
    const int quad = lane >> 4, l16 = lane & 15;
    const float scale2 = 0.08838834764831845f * 1.4426950408889634f;  // scale * log2(e)

    // Q fragments (A-layout): lane holds Q[row=l16][d=kc*32+quad*8+j]
    bf16x8 qf[2][4];
    const int qrow0 = qt*128 + w*32;
    #pragma unroll
    for (int tm = 0; tm < 2; tm++){
        size_t base = ((size_t)(b*SEQ + qrow0 + tm*16 + l16) * NH + h) * HD;
        #pragma unroll
        for (int kc = 0; kc < 4; kc++)
            qf[tm][kc] = *(const bf16x8*)&q[base + kc*32 + quad*8];
    }

    f32x4 oacc[2][8];
    float m_i[2][4], l_i[2][4];
    #pragma unroll
    for (int tm = 0; tm < 2; tm++){
        #pragma unroll
        for (int tn = 0; tn < 8; tn++) oacc[tm][tn] = (f32x4){0.f, 0.f, 0.f, 0.f};
        #pragma unroll
        for (int r = 0; r < 4; r++){ m_i[tm][r] = -1e30f; l_i[tm][r] = 0.f; }
    }

    const int ktmax = 2*qt + 1;
    for (int kt = 0; kt <= ktmax; kt++){
        __syncthreads();   // prev iter's K/V reads done before DMA overwrite
        #pragma unroll
        for (int i = 0; i < 4; i++){
            int kc = w*4 + i;
            const unsigned short* gp = k + ((size_t)((b*SEQ + kt*64 + lane)*NKV + g))*HD + kc*8;
            gload_lds16(gp, &Ks[kc*64*8]);
        }
        #pragma unroll
        for (int i = 0; i < 4; i++){
            int e = w*4 + i, kch = e >> 1, half = e & 1;
            const unsigned short* gp = vt + ((size_t)(b*NKV + g)*HD + half*64 + lane)*SEQ + kt*64 + kch*8;
            gload_lds16(gp, &Vs[(kch*128 + half*64)*8]);
        }
        __syncthreads();   // compiler drains vmcnt here

        // S = Q K^T : tiles [tm(2)][tn(4)], K-chunks kc(4)
        // B-frag for chunk kc: K[key=tn*16+l16][d=kc*32+quad*8+j] -> Ks chunk kc*4+quad
        f32x4 sacc[2][4];
        #pragma unroll
        for (int tm = 0; tm < 2; tm++)
            #pragma unroll
            for (int tn = 0; tn < 4; tn++) sacc[tm][tn] = (f32x4){0.f, 0.f, 0.f, 0.f};
        #pragma unroll
        for (int kc = 0; kc < 4; kc++){
            bf16x8 kf[4];
            #pragma unroll
            for (int tn = 0; tn < 4; tn++)
                kf[tn] = *(const bf16x8*)&Ks[((kc*4 + quad)*64 + tn*16 + l16)*8];
            #pragma unroll
            for (int tm = 0; tm < 2; tm++)
                #pragma unroll
                for (int tn = 0; tn < 4; tn++)
                    sacc[tm][tn] = __builtin_amdgcn_mfma_f32_16x16x32_bf16(qf[tm][kc], kf[tn], sacc[tm][tn], 0, 0, 0);
        }

        // online softmax in exp2 domain; lane holds S[row=quad*4+r][col=l16] per tile
        const int kbase = kt*64;
        #pragma unroll
        for (int tm = 0; tm < 2; tm++){
            #pragma unroll
            for (int r = 0; r < 4; r++){
                int qrow = qrow0 + tm*16 + quad*4 + r;
                float sv[4];
                #pragma unroll
                for (int tn = 0; tn < 4; tn++){
                    float s = sacc[tm][tn][r] * scale2;
                    if (kbase + tn*16 + l16 > qrow) s = -1e9f;
                    sv[tn] = s;
                }
                float rm = fmaxf(fmaxf(sv[0], sv[1]), fmaxf(sv[2], sv[3]));
                rm = fmaxf(rm, __shfl_xor(rm, 1));
                rm = fmaxf(rm, __shfl_xor(rm, 2));
                rm = fmaxf(rm, __shfl_xor(rm, 4));
                rm = fmaxf(rm, __shfl_xor(rm, 8));
                float newm = fmaxf(m_i[tm][r], rm);
                float alpha = exp2f(m_i[tm][r] - newm);
                m_i[tm][r] = newm;
                float rs = 0.f;
                #pragma unroll
                for (int tn = 0; tn < 4; tn++){
                    float p = exp2f(sv[tn] - newm);
                    rs += p;
                    Ps[(w*32 + tm*16 + quad*4 + r)*72 + tn*16 + l16] = f2bf(p);
                }
                rs += __shfl_xor(rs, 1);
                rs += __shfl_xor(rs, 2);
                rs += __shfl_xor(rs, 4);
                rs += __shfl_xor(rs, 8);
                l_i[tm][r] = l_i[tm][r] * alpha + rs;
                #pragma unroll
                for (int tn = 0; tn < 8; tn++) oacc[tm][tn][r] *= alpha;
            }
        }

        // O += P V : A-frags from Ps (wave-private, no barrier), B-frags from Vs
        #pragma unroll
        for (int ks = 0; ks < 2; ks++){
            bf16x8 pf[2];
            #pragma unroll
            for (int tm = 0; tm < 2; tm++)
                pf[tm] = *(const bf16x8*)&Ps[(w*32 + tm*16 + l16)*72 + ks*32 + quad*8];
            #pragma unroll
            for (int tn = 0; tn < 8; tn++){
                bf16x8 vf = *(const bf16x8*)&Vs[((ks*4 + quad)*128 + tn*16 + l16)*8];
                #pragma unroll
                for (int tm = 0; tm < 2; tm++)
                    oacc[tm][tn] = __builtin_amdgcn_mfma_f32_16x16x32_bf16(pf[tm], vf, oacc[tm][tn], 0, 0, 0);
            }
        }
    }

    // epilogue
    #pragma unroll
    for (int tm = 0; tm < 2; tm++){
        #pragma unroll
        for (int r = 0; r < 4; r++){
            float inv = 1.f / l_i[tm][r];
            size_t base = ((size_t)(b*SEQ + qrow0 + tm*16 + quad*4 + r) * NH + h) * HD;
            #pragma unroll
            for (int tn = 0; tn < 8; tn++)
                ao[base + tn*16 + l16] = f2bf(oacc[tm][tn][r] * inv);
        }
    }
}

extern "C" void kernel_launch(void* const* d_in, const int* in_sizes, int n_in,
                              void* d_out, int out_size, void* d_ws, size_t ws_size,
                              hipStream_t stream){
    const float* hs   = (const float*)d_in[0];
    const float* cosp = (const float*)d_in[1];
    const float* sinp = (const float*)d_in[2];
    const float* Wq   = (const float*)d_in[3];
    const float* bq   = (const float*)d_in[4];
    const float* Wk   = (const float*)d_in[5];
    const float* bk   = (const float*)d_in[6];
    const float* Wv   = (const float*)d_in[7];
    const float* bv   = (const float*)d_in[8];
    const float* Wo   = (const float*)d_in[9];
    float* out = (float*)d_out;
    char* ws = (char*)d_ws;

    // workspace layout (bytes)
    unsigned short* hsb = (unsigned short*)(ws + 0);          // 4096x3584 bf16
    unsigned short* Wqt = (unsigned short*)(ws + 29360128);   // 3584x3584 bf16
    unsigned short* Wkt = (unsigned short*)(ws + 55050240);   //  512x3584 bf16
    unsigned short* Wvt = (unsigned short*)(ws + 58720256);   //  512x3584 bf16
    unsigned short* qb  = (unsigned short*)(ws + 62390272);   // 4096x3584 bf16
    unsigned short* kb  = (unsigned short*)(ws + 91750400);   // 4096x512  bf16
    unsigned short* vb  = (unsigned short*)(ws + 95944704);   // 4096x512  bf16
    unsigned short* ao  = hsb;                 // reuse: hsb consumed by QKV gemms
    unsigned short* Wot = Wqt;                 // reuse: Wqt consumed by Q gemm
    unsigned short* vtb = (unsigned short*)(ws + 55050240);   // reuse Wkt/Wvt: 2x512x2048 bf16

    int n4 = MTOK * HIDDEN / 4;
    cast_f32_bf16<<<(n4 + 255) / 256, 256, 0, stream>>>(hs, hsb, n4);
    transpose_cast<<<dim3(112, 112), dim3(32, 8), 0, stream>>>(Wq, Wqt, HIDDEN, NH*HD);
    transpose_cast<<<dim3(16, 112),  dim3(32, 8), 0, stream>>>(Wk, Wkt, HIDDEN, NKV*HD);
    transpose_cast<<<dim3(16, 112),  dim3(32, 8), 0, stream>>>(Wv, Wvt, HIDDEN, NKV*HD);

    gemm_bt<1><<<dim3(32, 28), 256, 0, stream>>>(hsb, Wqt, bq, qb, MTOK, NH*HD,  HIDDEN);
    gemm_bt<1><<<dim3(32, 4),  256, 0, stream>>>(hsb, Wkt, bk, kb, MTOK, NKV*HD, HIDDEN);
    gemm_bt<1><<<dim3(32, 4),  256, 0, stream>>>(hsb, Wvt, bv, vb, MTOK, NKV*HD, HIDDEN);

    rope_kernel<<<(MTOK*NH*64  + 255) / 256, 256, 0, stream>>>(qb, cosp, sinp, NH,  MTOK*NH*64);
    rope_kernel<<<(MTOK*NKV*64 + 255) / 256, 256, 0, stream>>>(kb, cosp, sinp, NKV, MTOK*NKV*64);

    // v -> vt (overwrites Wkt/Wvt region; K/V gemms already done)
    transpose_v<<<dim3(64, 16, 2), dim3(32, 8), 0, stream>>>(vb, vtb);

    transpose_cast<<<dim3(112, 112), dim3(32, 8), 0, stream>>>(Wo, Wot, NH*HD, HIDDEN);

    attn_mfma<<<dim3(16, 28, 2), 256, 0, stream>>>(qb, kb, vtb, ao);

    gemm_bt<0><<<dim3(32, 28), 256, 0, stream>>>(ao, Wot, nullptr, out, MTOK, HIDDEN, NH*HD);
}

// Round 4
// 759.654 us; speedup vs baseline: 3.2760x; 1.4293x over previous
//
#include <hip/hip_runtime.h>

#define HIDDEN 3584
#define NH 28
#define NKV 4
#define HD 128
#define NREP 7
#define SEQ 2048
#define BATCH 2
#define MTOK (BATCH*SEQ)   // 4096
#define QKVN 4608          // 3584 + 512 + 512
#define SCALE2 0.12751744f // 128^-0.5 * log2(e), folded into Q at RoPE

typedef __bf16 bf16x8 __attribute__((ext_vector_type(8)));
typedef float  f32x4  __attribute__((ext_vector_type(4)));

__device__ __forceinline__ unsigned short f2bf(float f){
    unsigned u = __builtin_bit_cast(unsigned, f);
    unsigned r = u + 0x7FFFu + ((u >> 16) & 1u);   // RNE
    return (unsigned short)(r >> 16);
}
__device__ __forceinline__ float bf2f(unsigned short h){
    unsigned u = ((unsigned)h) << 16;
    return __builtin_bit_cast(float, u);
}

// async global->LDS, 16B per lane; lds dest = wave-uniform base + lane*16
__device__ __forceinline__ void gload_lds16(const void* g, void* l){
    __builtin_amdgcn_global_load_lds(
        (const __attribute__((address_space(1))) void*)g,
        (__attribute__((address_space(3))) void*)l, 16, 0, 0);
}

// ---------------- elementwise cast fp32 -> bf16 ----------------
__global__ void cast_f32_bf16(const float* __restrict__ x, unsigned short* __restrict__ y, int n4){
    int i = blockIdx.x * blockDim.x + threadIdx.x;
    if (i < n4){
        float4 v = ((const float4*)x)[i];
        ushort4 o; o.x=f2bf(v.x); o.y=f2bf(v.y); o.z=f2bf(v.z); o.w=f2bf(v.w);
        ((ushort4*)y)[i] = o;
    }
}

// ---------------- W [K][N] fp32 -> Wt [N][K] bf16 ----------------
__global__ void transpose_cast(const float* __restrict__ W, unsigned short* __restrict__ Wt,
                               int K, int N){
    __shared__ float t[32][33];
    int n0 = blockIdx.x * 32, k0 = blockIdx.y * 32;
    int tx = threadIdx.x, ty = threadIdx.y;      // (32,8)
    #pragma unroll
    for (int r = 0; r < 4; r++)
        t[ty + r*8][tx] = W[(size_t)(k0 + ty + r*8) * N + n0 + tx];
    __syncthreads();
    #pragma unroll
    for (int r = 0; r < 4; r++)
        Wt[(size_t)(n0 + ty + r*8) * K + k0 + tx] = f2bf(t[tx][ty + r*8]);
}

// ---------------- V columns of qkv [B*S][4608] -> vt [B*512][SEQ] bf16 ----------------
__global__ void transpose_v(const unsigned short* __restrict__ qkv, unsigned short* __restrict__ vt){
    __shared__ unsigned short t[32][33];
    int s0 = blockIdx.x * 32, c0 = blockIdx.y * 32, b = blockIdx.z;
    int tx = threadIdx.x, ty = threadIdx.y;      // (32,8)
    #pragma unroll
    for (int r = 0; r < 4; r++)
        t[ty + r*8][tx] = qkv[(size_t)(b*SEQ + s0 + ty + r*8) * QKVN + 4096 + c0 + tx];
    __syncthreads();
    #pragma unroll
    for (int r = 0; r < 4; r++)
        vt[(size_t)(b*NKV*HD + c0 + ty + r*8) * SEQ + s0 + tx] = t[tx][ty + r*8];
}

// ---------------- GEMM: C[M,N] = A[M,K] @ Bt[N,K]^T + bias (triple-segment) ----------------
// m97 structure: 128x128 tile, BK=32, global_load_lds width-16, unpadded LDS.
template<int OUT_BF16>
__global__ __launch_bounds__(256) void gemm_bt(const unsigned short* __restrict__ A,
                                               const unsigned short* __restrict__ Bt,
                                               const float* __restrict__ bias,
                                               const float* __restrict__ bias2,
                                               const float* __restrict__ bias3,
                                               int nb1, int nb2,
                                               void* __restrict__ C, int M, int N, int K){
    __shared__ unsigned short As[128*32];
    __shared__ unsigned short Bs[128*32];
    int tid = threadIdx.x;
    int bm = blockIdx.x, bn = blockIdx.y;
    int lane = tid & 63, wave = tid >> 6;
    int wm = wave >> 1, wn = wave & 1;
    int quad = lane >> 4, l16 = lane & 15;
    f32x4 acc[4][4] = {};
    const unsigned short* Ag = A  + (size_t)(bm*128) * K;
    const unsigned short* Bg = Bt + (size_t)(bn*128) * K;

    for (int k0 = 0; k0 < K; k0 += 32){
        __syncthreads();
        #pragma unroll
        for (int c = 0; c < 2; c++){
            int e = c*256 + tid;                 // 0..511
            int r = e >> 2, col = (e & 3) * 8;
            int lb = (c*256 + wave*64) * 8;      // wave-uniform LDS base (elems)
            gload_lds16(&Ag[(size_t)r*K + k0 + col], &As[lb]);
            gload_lds16(&Bg[(size_t)r*K + k0 + col], &Bs[lb]);
        }
        __syncthreads();
        bf16x8 af[4], bf[4];
        #pragma unroll
        for (int t = 0; t < 4; t++){
            af[t] = *(const bf16x8*)&As[(wm*64 + t*16 + l16)*32 + quad*8];
            bf[t] = *(const bf16x8*)&Bs[(wn*64 + t*16 + l16)*32 + quad*8];
        }
        #pragma unroll
        for (int tm = 0; tm < 4; tm++)
            #pragma unroll
            for (int tn = 0; tn < 4; tn++)
                acc[tm][tn] = __builtin_amdgcn_mfma_f32_16x16x32_bf16(af[tm], bf[tn], acc[tm][tn], 0, 0, 0);
    }
    // epilogue: D row = quad*4 + r, col = l16
    #pragma unroll
    for (int tn = 0; tn < 4; tn++){
        int col = bn*128 + wn*64 + tn*16 + l16;
        float bb = 0.f;
        if (bias){
            if (col < nb1)      bb = bias[col];
            else if (col < nb2) bb = bias2[col - nb1];
            else                bb = bias3[col - nb2];
        }
        #pragma unroll
        for (int tm = 0; tm < 4; tm++){
            int row0 = bm*128 + wm*64 + tm*16 + quad*4;
            #pragma unroll
            for (int r = 0; r < 4; r++){
                float v = acc[tm][tn][r] + bb;
                if (OUT_BF16) ((unsigned short*)C)[(size_t)(row0+r)*N + col] = f2bf(v);
                else          ((float*)C)[(size_t)(row0+r)*N + col] = v;
            }
        }
    }
}

// ---------------- RoPE in-place on bf16, generic row stride ----------------
__global__ void rope_kernel(unsigned short* __restrict__ x, const float* __restrict__ cosp,
                            const float* __restrict__ sinp, int nheads, int rowstride,
                            float outscale, int total){
    int i = blockIdx.x * blockDim.x + threadIdx.x;
    if (i >= total) return;
    int d   = i & 63;
    int h   = (i >> 6) % nheads;
    int row = i / (64 * nheads);
    int s   = row & (SEQ - 1);
    size_t base = (size_t)row * rowstride + h * HD;
    float x1 = bf2f(x[base + d]), x2 = bf2f(x[base + d + 64]);
    float c1 = cosp[s*HD + d],  c2 = cosp[s*HD + d + 64];
    float s1 = sinp[s*HD + d],  s2 = sinp[s*HD + d + 64];
    x[base + d]      = f2bf((x1 * c1 - x2 * s1) * outscale);
    x[base + d + 64] = f2bf((x2 * c2 + x1 * s2) * outscale);
}

// ---------------- MFMA flash attention, balanced + drain-free pipeline ----------------
// grid (8 pairs, 28 heads, 2 batch), 256 threads = 4 waves.
// Block p processes qt = 15-p then qt = p  -> exactly 34 K-iters per block.
// Ks[2]: double-buffered [kc8(16)][key(64)][8]; DMA(kt+1) issued at iter top,
// consumed next iter -> vmcnt(0) drain at barriers is fully covered by compute.
// Vs: single [kch(8)][d(128)][8]; DMA at iter top, read after b1 (~900cyc to land).
// Ps: [qrow(128)][64] bf16, XOR-swizzled (tn^quad on 16-col group) -> conflict-free.
__global__ __launch_bounds__(256, 2) void attn_mfma(const unsigned short* __restrict__ qkv,
                                                    const unsigned short* __restrict__ vt,
                                                    unsigned short* __restrict__ ao){
    __shared__ unsigned short Ks[2][16*64*8];
    __shared__ unsigned short Vs[8*128*8];
    __shared__ unsigned short Ps[128*64];
    const int h = blockIdx.y, b = blockIdx.z;
    const int g = h / NREP;
    const int tid = threadIdx.x;
    const int lane = tid & 63, w = tid >> 6;
    const int quad = lane >> 4, l16 = lane & 15;

    // DMA source bases (lane-fixed parts)
    const unsigned short* kdma  = qkv + (size_t)(b*SEQ + lane)*QKVN + 3584 + g*HD;
    const unsigned short* vdma0 = vt  + ((size_t)(b*NKV + g)*HD + lane)*SEQ;

    for (int ph = 0; ph < 2; ph++){
        const int qt = ph ? (int)blockIdx.x : (15 - (int)blockIdx.x);
        const int qrow0 = qt*128 + w*32;

        // Q fragments (A-layout, scale pre-folded by RoPE): lane holds Q[row=l16][d=kc*32+quad*8+j]
        bf16x8 qf[2][4];
        #pragma unroll
        for (int tm = 0; tm < 2; tm++){
            const unsigned short* qp = qkv + (size_t)(b*SEQ + qrow0 + tm*16 + l16)*QKVN + h*HD;
            #pragma unroll
            for (int kc = 0; kc < 4; kc++)
                qf[tm][kc] = *(const bf16x8*)&qp[kc*32 + quad*8];
        }

        f32x4 oacc[2][8];
        float m_i[2][4], l_i[2][4];
        #pragma unroll
        for (int tm = 0; tm < 2; tm++){
            #pragma unroll
            for (int tn = 0; tn < 8; tn++) oacc[tm][tn] = (f32x4){0.f, 0.f, 0.f, 0.f};
            #pragma unroll
            for (int r = 0; r < 4; r++){ m_i[tm][r] = -1e30f; l_i[tm][r] = 0.f; }
        }

        const int ktmax = 2*qt + 1;
        // prologue: DMA K(0) -> Ks[0]
        #pragma unroll
        for (int i = 0; i < 4; i++){
            int kc = w*4 + i;
            gload_lds16(kdma + kc*8, &Ks[0][kc*64*8]);
        }
        __syncthreads();   // drain K0 (once per phase)

        int cur = 0;
        for (int kt = 0; kt <= ktmax; kt++){
            // issue next-iteration K DMA into the other buffer (freed by prev b2)
            if (kt < ktmax){
                const unsigned short* kp = kdma + (size_t)((kt+1)*64)*QKVN;
                #pragma unroll
                for (int i = 0; i < 4; i++){
                    int kc = w*4 + i;
                    gload_lds16(kp + kc*8, &Ks[cur^1][kc*64*8]);
                }
            }
            // V DMA for this kt (Vs freed by prev b2; consumed after b1 below)
            #pragma unroll
            for (int i = 0; i < 4; i++){
                int e = w*4 + i, kch = e >> 1, half = e & 1;
                gload_lds16(vdma0 + (size_t)(half*64)*SEQ + kt*64 + kch*8,
                            &Vs[(kch*128 + half*64)*8]);
            }

            // S = Q K^T from Ks[cur] (DMA'd last iter, drained at prev barrier)
            f32x4 sacc[2][4];
            #pragma unroll
            for (int tm = 0; tm < 2; tm++)
                #pragma unroll
                for (int tn = 0; tn < 4; tn++) sacc[tm][tn] = (f32x4){0.f, 0.f, 0.f, 0.f};
            #pragma unroll
            for (int kc = 0; kc < 4; kc++){
                bf16x8 kf[4];
                #pragma unroll
                for (int tn = 0; tn < 4; tn++)
                    kf[tn] = *(const bf16x8*)&Ks[cur][((kc*4 + quad)*64 + tn*16 + l16)*8];
                #pragma unroll
                for (int tm = 0; tm < 2; tm++)
                    #pragma unroll
                    for (int tn = 0; tn < 4; tn++)
                        sacc[tm][tn] = __builtin_amdgcn_mfma_f32_16x16x32_bf16(qf[tm][kc], kf[tn], sacc[tm][tn], 0, 0, 0);
            }

            // online softmax (exp2 domain; scale pre-folded into Q)
            const int kbase = kt*64;
            const bool need_mask = (kbase + 63 > qrow0);   // wave-uniform
            #pragma unroll
            for (int tm = 0; tm < 2; tm++){
                #pragma unroll
                for (int r = 0; r < 4; r++){
                    float sv[4];
                    #pragma unroll
                    for (int tn = 0; tn < 4; tn++) sv[tn] = sacc[tm][tn][r];
                    if (need_mask){
                        int qrow = qrow0 + tm*16 + quad*4 + r;
                        #pragma unroll
                        for (int tn = 0; tn < 4; tn++)
                            if (kbase + tn*16 + l16 > qrow) sv[tn] = -1e9f;
                    }
                    float rm = fmaxf(fmaxf(sv[0], sv[1]), fmaxf(sv[2], sv[3]));
                    rm = fmaxf(rm, __shfl_xor(rm, 1));
                    rm = fmaxf(rm, __shfl_xor(rm, 2));
                    rm = fmaxf(rm, __shfl_xor(rm, 4));
                    rm = fmaxf(rm, __shfl_xor(rm, 8));
                    float newm = fmaxf(m_i[tm][r], rm);
                    float alpha = exp2f(m_i[tm][r] - newm);
                    m_i[tm][r] = newm;
                    float rs = 0.f;
                    int prow = (w*32 + tm*16 + quad*4 + r)*64;
                    #pragma unroll
                    for (int tn = 0; tn < 4; tn++){
                        float p = exp2f(sv[tn] - newm);
                        rs += p;
                        Ps[prow + ((tn ^ quad) << 4) + l16] = f2bf(p);
                    }
                    l_i[tm][r] = l_i[tm][r] * alpha + rs;   // lane-partial l (reduced at epilogue)
                    #pragma unroll
                    for (int tn = 0; tn < 8; tn++) oacc[tm][tn][r] *= alpha;
                }
            }
            __syncthreads();   // b1: V ready (DMA had QK^T+softmax to land), K(kt+1) drained early

            // O += P V : A-frags from swizzled Ps (wave-private rows), B-frags from Vs
            #pragma unroll
            for (int ks = 0; ks < 2; ks++){
                bf16x8 pf[2];
                #pragma unroll
                for (int tm = 0; tm < 2; tm++){
                    int prow = (w*32 + tm*16 + l16)*64;
                    int sw = (((2*ks + (quad >> 1)) ^ (l16 >> 2)) << 4) + (quad & 1)*8;
                    pf[tm] = *(const bf16x8*)&Ps[prow + sw];
                }
                #pragma unroll
                for (int tn = 0; tn < 8; tn++){
                    bf16x8 vf = *(const bf16x8*)&Vs[((ks*4 + quad)*128 + tn*16 + l16)*8];
                    #pragma unroll
                    for (int tm = 0; tm < 2; tm++)
                        oacc[tm][tn] = __builtin_amdgcn_mfma_f32_16x16x32_bf16(pf[tm], vf, oacc[tm][tn], 0, 0, 0);
                }
            }
            __syncthreads();   // b2: frees Vs & Ks[cur]; nothing outstanding -> no drain
            cur ^= 1;
        }

        // epilogue: reduce lane-partial l across the row's 16 lanes, write ao
        #pragma unroll
        for (int tm = 0; tm < 2; tm++){
            #pragma unroll
            for (int r = 0; r < 4; r++){
                float lt = l_i[tm][r];
                lt += __shfl_xor(lt, 1);
                lt += __shfl_xor(lt, 2);
                lt += __shfl_xor(lt, 4);
                lt += __shfl_xor(lt, 8);
                float inv = 1.f / lt;
                size_t base = ((size_t)(b*SEQ + qrow0 + tm*16 + quad*4 + r)) * (NH*HD) + h*HD;
                #pragma unroll
                for (int tn = 0; tn < 8; tn++)
                    ao[base + tn*16 + l16] = f2bf(oacc[tm][tn][r] * inv);
            }
        }
    }
}

extern "C" void kernel_launch(void* const* d_in, const int* in_sizes, int n_in,
                              void* d_out, int out_size, void* d_ws, size_t ws_size,
                              hipStream_t stream){
    const float* hs   = (const float*)d_in[0];
    const float* cosp = (const float*)d_in[1];
    const float* sinp = (const float*)d_in[2];
    const float* Wq   = (const float*)d_in[3];
    const float* bq   = (const float*)d_in[4];
    const float* Wk   = (const float*)d_in[5];
    const float* bk   = (const float*)d_in[6];
    const float* Wv   = (const float*)d_in[7];
    const float* bv   = (const float*)d_in[8];
    const float* Wo   = (const float*)d_in[9];
    float* out = (float*)d_out;
    char* ws = (char*)d_ws;

    // workspace layout (bytes)
    unsigned short* hsb  = (unsigned short*)(ws + 0);          // 4096x3584 bf16 = 29,360,128
    unsigned short* Wqt  = (unsigned short*)(ws + 29360128);   // 3584x3584 bf16 (Wq^T)
    unsigned short* Wkt  = (unsigned short*)(ws + 55050240);   //  512x3584 bf16 (contiguous after Wqt)
    unsigned short* Wvt  = (unsigned short*)(ws + 58720256);   //  512x3584 bf16 (contiguous after Wkt)
    unsigned short* qkvb = (unsigned short*)(ws + 62390272);   // 4096x4608 bf16 = 37,748,736
    unsigned short* ao   = hsb;                                // reuse: hsb consumed by QKV gemm
    unsigned short* Wot  = Wqt;                                // reuse: W^T block consumed by QKV gemm
    unsigned short* vtb  = (unsigned short*)(ws + 55050240);   // reuse Wkt/Wvt: 2x512x2048 bf16

    int n4 = MTOK * HIDDEN / 4;
    cast_f32_bf16<<<(n4 + 255) / 256, 256, 0, stream>>>(hs, hsb, n4);
    transpose_cast<<<dim3(112, 112), dim3(32, 8), 0, stream>>>(Wq, Wqt, HIDDEN, NH*HD);
    transpose_cast<<<dim3(16, 112),  dim3(32, 8), 0, stream>>>(Wk, Wkt, HIDDEN, NKV*HD);
    transpose_cast<<<dim3(16, 112),  dim3(32, 8), 0, stream>>>(Wv, Wvt, HIDDEN, NKV*HD);

    // fused QKV projection: Bt = [Wqt;Wkt;Wvt] (contiguous), N = 4608
    gemm_bt<1><<<dim3(32, 36), 256, 0, stream>>>(hsb, Wqt, bq, bk, bv, 3584, 4096,
                                                 qkvb, MTOK, QKVN, HIDDEN);

    // RoPE: q gets softmax scale*log2(e) folded in; k plain
    rope_kernel<<<(MTOK*NH*64  + 255) / 256, 256, 0, stream>>>(qkvb,        cosp, sinp, NH,  QKVN, SCALE2, MTOK*NH*64);
    rope_kernel<<<(MTOK*NKV*64 + 255) / 256, 256, 0, stream>>>(qkvb + 3584, cosp, sinp, NKV, QKVN, 1.0f,   MTOK*NKV*64);

    // V columns -> vt (overwrites Wkt/Wvt region; QKV gemm already done)
    transpose_v<<<dim3(64, 16, 2), dim3(32, 8), 0, stream>>>(qkvb, vtb);

    transpose_cast<<<dim3(112, 112), dim3(32, 8), 0, stream>>>(Wo, Wot, NH*HD, HIDDEN);

    attn_mfma<<<dim3(8, 28, 2), 256, 0, stream>>>(qkvb, vtb, ao);

    gemm_bt<0><<<dim3(32, 28), 256, 0, stream>>>(ao, Wot, nullptr, nullptr, nullptr, 1<<30, 1<<30,
                                                 out, MTOK, HIDDEN, NH*HD);
}